// Round 3
// baseline (212.414 us; speedup 1.0000x reference)
//
#include <hip/hip_runtime.h>

#define NUM_INST 64
#define SLOT 12      // floats per routing slot: 8 used, 48B stride keeps 16B alignment
#define BLOCK 256
#define NWAVES 4
#define GRID 2048    // 8 blocks/CU on 256 CUs
#define K 4          // elements per thread per outer iteration (MLP)

__global__ __launch_bounds__(BLOCK) void vsl_main(const float4* __restrict__ rows,
                                                  const int* __restrict__ labels,
                                                  float* __restrict__ gacc, int n) {
    // per-wave private routing buffer: 64 slots x 12 floats (no cross-wave sharing -> no barriers)
    __shared__ float lds[NWAVES][NUM_INST * SLOT];
    const int tid = threadIdx.x;
    const int w = tid >> 6;
    const int lane = tid & 63;

    // lane d of each wave owns label d: accumulate its stats in registers
    float s0 = 0, s1 = 0, s2 = 0, s3 = 0, s4 = 0, s5 = 0, s6 = 0, s7 = 0;
    float ssq = 0, cntf = 0;

    float* slotbase = &lds[w][lane * SLOT];
    const int S = GRID * BLOCK;

    for (int i0 = blockIdx.x * BLOCK + tid;; i0 += S * K) {
        bool val[K];
        int lbl[K];
        float4 a[K], b[K];
        bool anyv = false;
#pragma unroll
        for (int k = 0; k < K; ++k) {
            const int i = i0 + k * S;
            val[k] = (i < n);
            anyv |= val[k];
        }
        // uniform exit: every lane leaves only when NO lane anywhere has work
        if (!__ballot(anyv)) break;

        // issue all independent loads first (12 coalesced loads in flight)
#pragma unroll
        for (int k = 0; k < K; ++k) {
            const int i = i0 + k * S;
            if (val[k]) {
                lbl[k] = labels[i];
                a[k] = rows[2 * i];
                b[k] = rows[2 * i + 1];
            } else {
                lbl[k] = 0;
                a[k] = make_float4(0, 0, 0, 0);
                b[k] = make_float4(0, 0, 0, 0);
            }
        }

#pragma unroll
        for (int k = 0; k < K; ++k) {
            const unsigned long long bv = __ballot(val[k]);
            if (!bv) continue;  // wave-uniform

            // publish my element to my private slot (plain DS writes, no atomics)
            *(float4*)(slotbase) = a[k];
            *(float4*)(slotbase + 4) = b[k];

            // 6 ballots on label bits -> mask of source lanes whose label == my lane id
            unsigned long long m = bv;
#pragma unroll
            for (int bpos = 0; bpos < 6; ++bpos) {
                const unsigned long long bb = __ballot((lbl[k] >> bpos) & 1);
                m &= ((lane >> bpos) & 1) ? bb : ~bb;
            }
            cntf += (float)__popcll(m);  // exact integer counts

            // slot writes must land before gathering; memory clobber stops reordering
            asm volatile("s_waitcnt lgkmcnt(0)" ::: "memory");

            while (m) {
                const int s = (int)__builtin_ctzll(m);
                m &= m - 1;
                const float* sp = &lds[w][s * SLOT];
                const float4 p = *(const float4*)sp;
                const float4 q = *(const float4*)(sp + 4);
                s0 += p.x; s1 += p.y; s2 += p.z; s3 += p.w;
                s4 += q.x; s5 += q.y; s6 += q.z; s7 += q.w;
                ssq += p.x * p.x + p.y * p.y + p.z * p.z + p.w * p.w +
                       q.x * q.x + q.y * q.y + q.z * q.z + q.w * q.w;
            }
        }
    }

    // flush: reuse the routing buffer for the per-wave totals (own region, own wave -> safe)
    float* fb = &lds[w][lane * SLOT];
    fb[0] = s0; fb[1] = s1; fb[2] = s2; fb[3] = s3;
    fb[4] = s4; fb[5] = s5; fb[6] = s6; fb[7] = s7;
    fb[8] = ssq; fb[9] = cntf;
    __syncthreads();

    // cross-wave reduce + one global atomic per (label, stat) per block
    for (int j = tid; j < NUM_INST * 10; j += BLOCK) {
        const int lbl = j / 10;
        const int st = j - lbl * 10;
        float v = 0;
#pragma unroll
        for (int ww = 0; ww < NWAVES; ++ww) v += lds[ww][lbl * SLOT + st];
        atomicAdd(&gacc[j], v);
    }
}

__global__ __launch_bounds__(64) void vsl_final(const float* __restrict__ gacc,
                                                float* __restrict__ out) {
    const int s = threadIdx.x;  // one thread per instance, 1 wave
    float val = 0.0f;
    const float* base = &gacc[s * 10];
    const float cnt = base[9];
    if (s != 0 && cnt > 0.0f) {
        const float ss = base[8];
        float m2 = 0.0f;
#pragma unroll
        for (int d = 0; d < 8; ++d) {
            const float sd = base[d];
            m2 += sd * sd;
        }
        val = (ss - m2 / cnt) / (cnt * 8.0f);
    }
#pragma unroll
    for (int off = 32; off > 0; off >>= 1) val += __shfl_down(val, off, 64);
    if (s == 0) out[0] = val;
}

extern "C" void kernel_launch(void* const* d_in, const int* in_sizes, int n_in,
                              void* d_out, int out_size, void* d_ws, size_t ws_size,
                              hipStream_t stream) {
    const float* variances = (const float*)d_in[0];  // [N, 8] fp32
    const int* labels = (const int*)d_in[1];         // [N] int32
    const int n = in_sizes[1];                       // N
    float* gacc = (float*)d_ws;                      // 640 floats of scratch

    hipMemsetAsync(d_ws, 0, NUM_INST * 10 * sizeof(float), stream);
    vsl_main<<<GRID, BLOCK, 0, stream>>>((const float4*)variances, labels, gacc, n);
    vsl_final<<<1, 64, 0, stream>>>(gacc, (float*)d_out);
}